// Round 8
// baseline (534.644 us; speedup 1.0000x reference)
//
#include <hip/hip_runtime.h>
#include <math.h>

// approxmatch EMD (Fan et al.) — b=8, n=m=2048, f32.
// R8: max-occupancy tiling. Block = 1024 threads = 32 rows x 32 j-slots
// (64 swept pts per lane); grid = 512 = 2 blocks/CU -> 32 waves/CU =
// 8 waves/SIMD (HW max). launch_bounds(1024,8) pins VGPR<=64.
// Cross-slot reduce: shfl_xor(32) then 16-wave x 32-row LDS matrix.
// Schedule (22 dispatches): prep | A0 | 10 x { B_t ; CA_t or C9 }.
//   A: f_i = remL_i/(1e-9 + sum_j e(kk)R_j)
//   B: s_j = sum_i f_i e(kk); colsum=R s; rr=min(R/(1e-9+colsum),1); c=R rr;
//      R' = max(R-colsum rr,0)
//   C: t_i=sum_j c e; u_i=sum_j c e sqrt(d2); remL'=max(remL-f t,0); cost+=f u
// CA_t fuses C_t with A_{t+1} (level_t = 4*level_{t+1} exactly for t<8):
// one exp e1=exp2(kk_{t+1} d2) serves C (e1^4) and A (e1).
// Folded exponent: kk*d2 = kk|p|^2 + kk|q|^2 - 2kk(p.q); sqrt(d2) =
// sqrt(|kk*d2|)/sqrt(|kk|), constant hoisted.

#define NPTS 2048
#define BT 1024
#define NW 16                 // waves per block
#define RPB 32                // rows (or cols) per block
#define JCHUNK 64             // swept indices per lane (2048 / 32 slots)
#define L2E 1.4426950408889634f

__device__ __forceinline__ float fexp2(float x) { return __builtin_amdgcn_exp2f(x); }
__device__ __forceinline__ float fsqrt(float x) { return __builtin_amdgcn_sqrtf(x); }

// Pack points as (x,y,z,|p|^2); zero the output accumulators.
__global__ void k_prep(const float* __restrict__ xyz1, const float* __restrict__ xyz2,
                       float4* __restrict__ S1, float4* __restrict__ S2,
                       float* __restrict__ out, int bn, int bm, int nout) {
    int i = blockIdx.x * 256 + threadIdx.x;
    if (i < bn) {
        const float* p = xyz1 + 3 * (size_t)i;
        float x = p[0], y = p[1], z = p[2];
        S1[i] = make_float4(x, y, z, x*x + y*y + z*z);
    }
    if (i < bm) {
        const float* p = xyz2 + 3 * (size_t)i;
        float x = p[0], y = p[1], z = p[2];
        S2[i] = make_float4(x, y, z, x*x + y*y + z*z);
    }
    if (i < nout) out[i] = 0.f;
}

// Level-0 rows pass: f_i = multiL / (1e-9 + multiR * sum_j e(kk)).
__global__ __launch_bounds__(BT, 8) void k_A0(
    const float4* __restrict__ S1, const float4* __restrict__ S2,
    float* __restrict__ f_g, float kk, float multiL, float multiR)
{
    __shared__ float red[NW * RPB];
    const int row0 = blockIdx.x * RPB;
    const int batch = row0 >> 11;
    const int rl_ = threadIdx.x & 31;
    const int jslot = threadIdx.x >> 5;
    const int wave = threadIdx.x >> 6;
    const int lane = threadIdx.x & 63;
    const float4* Q = S2 + ((size_t)batch << 11) + jslot * JCHUNK;
    float4 p = S1[row0 + rl_];
    float pa = kk * p.w, pxp = -2.f*kk*p.x, pyp = -2.f*kk*p.y, pzp = -2.f*kk*p.z;
    float vkk = kk;
    float acc = 0.f;
#pragma unroll 4
    for (int j = 0; j < JCHUNK; ++j) {
        float4 q = Q[j];
        float t = fmaf(pxp, q.x, fmaf(pyp, q.y, fmaf(pzp, q.z, fmaf(vkk, q.w, pa))));
        acc += fexp2(t);
    }
    acc += __shfl_xor(acc, 32, 64);
    if (lane < 32) red[wave * RPB + lane] = acc;
    __syncthreads();
    if (threadIdx.x < RPB) {
        float s = 0.f;
#pragma unroll
        for (int w = 0; w < NW; ++w) s += red[w * RPB + threadIdx.x];
        f_g[row0 + threadIdx.x] = multiL / (1e-9f + multiR * s);
    }
}

// Cols pass: lane owns (col, islot); sweep rows i.
template <bool FIRST>
__global__ __launch_bounds__(BT, 8) void k_B(
    const float4* __restrict__ S1, const float4* __restrict__ S2,
    const float* __restrict__ f_g, float* __restrict__ remR,
    float* __restrict__ c_g, float kk, float multiR)
{
    __shared__ float red[NW * RPB];
    const int col0 = blockIdx.x * RPB;
    const int batch = col0 >> 11;
    const int cl_ = threadIdx.x & 31;
    const int islot = threadIdx.x >> 5;
    const int wave = threadIdx.x >> 6;
    const int lane = threadIdx.x & 63;
    const size_t bb = (size_t)batch << 11;
    const float4* P = S1 + bb + islot * JCHUNK;
    const float* F = f_g + bb + islot * JCHUNK;
    float4 q = S2[col0 + cl_];
    float ca = kk * q.w, cxp = -2.f*kk*q.x, cyp = -2.f*kk*q.y, czp = -2.f*kk*q.z;
    float vkk = kk;
    float acc = 0.f;
#pragma unroll 4
    for (int i = 0; i < JCHUNK; ++i) {
        float4 p = P[i];
        float fi = F[i];
        float t = fmaf(cxp, p.x, fmaf(cyp, p.y, fmaf(czp, p.z, fmaf(vkk, p.w, ca))));
        acc = fmaf(fi, fexp2(t), acc);
    }
    acc += __shfl_xor(acc, 32, 64);
    if (lane < 32) red[wave * RPB + lane] = acc;
    __syncthreads();
    if (threadIdx.x < RPB) {
        float s = 0.f;
#pragma unroll
        for (int w = 0; w < NW; ++w) s += red[w * RPB + threadIdx.x];
        int gj = col0 + threadIdx.x;
        float R = FIRST ? multiR : remR[gj];
        float colsum = R * s;
        float rr = fminf(R / (1e-9f + colsum), 1.0f);
        c_g[gj] = R * rr;
        remR[gj] = fmaxf(R - colsum * rr, 0.f);
    }
}

// Rows pass: C_t + fused A_{t+1}.
// MODE 1 (t<8): kp = kk_t/4 = kk_{t+1}; C-weight = e1^4; aA += R_j*e1.
// MODE 2 (t=8): kp = kk_8; C-weight = e1; aA += R_j (next level kk = 0).
template <int MODE, bool FIRSTC>
__global__ __launch_bounds__(BT, 8) void k_CA(
    const float4* __restrict__ S1, const float4* __restrict__ S2,
    float* __restrict__ f_g, const float* __restrict__ c_g,
    const float* __restrict__ remR, float* __restrict__ remL,
    float* __restrict__ costrow, float kp, float rsqkp, float multiL)
{
    __shared__ float redT[NW * RPB], redU[NW * RPB], redA[NW * RPB];
    const int row0 = blockIdx.x * RPB;
    const int batch = row0 >> 11;
    const int rl_ = threadIdx.x & 31;
    const int jslot = threadIdx.x >> 5;
    const int wave = threadIdx.x >> 6;
    const int lane = threadIdx.x & 63;
    const size_t bb = (size_t)batch << 11;
    const float4* Q = S2 + bb + jslot * JCHUNK;
    const float* C = c_g + bb + jslot * JCHUNK;
    const float* R = remR + bb + jslot * JCHUNK;
    float4 p = S1[row0 + rl_];
    float pa = kp * p.w, pxp = -2.f*kp*p.x, pyp = -2.f*kp*p.y, pzp = -2.f*kp*p.z;
    float vkp = kp;
    float aT = 0.f, aU = 0.f, aA = 0.f;
#pragma unroll 2
    for (int j = 0; j < JCHUNK; ++j) {
        float4 q = Q[j];
        float cw = C[j];
        float rw = R[j];
        float t = fmaf(pxp, q.x, fmaf(pyp, q.y, fmaf(pzp, q.z, fmaf(vkp, q.w, pa))));
        float e1 = fexp2(t);
        float eC;
        if (MODE == 1) { float e2 = e1 * e1; eC = cw * (e2 * e2); }
        else           { eC = cw * e1; }
        aT += eC;
        aU = fmaf(eC, fsqrt(fabsf(t)), aU);    // sqrt(d2) = sqrt(|t|)*rsqkp
        if (MODE == 1) aA = fmaf(rw, e1, aA);
        else           aA += rw;
    }
    aT += __shfl_xor(aT, 32, 64);
    aU += __shfl_xor(aU, 32, 64);
    aA += __shfl_xor(aA, 32, 64);
    if (lane < 32) {
        redT[wave * RPB + lane] = aT;
        redU[wave * RPB + lane] = aU;
        redA[wave * RPB + lane] = aA;
    }
    __syncthreads();
    if (threadIdx.x < RPB) {
        float tt = 0.f, uu = 0.f, aa = 0.f;
#pragma unroll
        for (int w = 0; w < NW; ++w) {
            tt += redT[w * RPB + threadIdx.x];
            uu += redU[w * RPB + threadIdx.x];
            aa += redA[w * RPB + threadIdx.x];
        }
        int gi = row0 + threadIdx.x;
        float fi = f_g[gi];
        float rl = fmaxf((FIRSTC ? multiL : remL[gi]) - fi * tt, 0.f);
        costrow[gi] = (FIRSTC ? 0.f : costrow[gi]) + fi * uu * rsqkp;
        remL[gi] = rl;
        f_g[gi] = rl / (1e-9f + aa);
    }
}

// Final level (kk=0): u_i = sum_j c_j sqrt(d2); out[batch] += costrow_i + f_i u_i.
__global__ __launch_bounds__(BT, 8) void k_C9(
    const float4* __restrict__ S1, const float4* __restrict__ S2,
    const float* __restrict__ f_g, const float* __restrict__ c_g,
    const float* __restrict__ costrow, float* __restrict__ out)
{
    __shared__ float redU[NW * RPB];
    const int row0 = blockIdx.x * RPB;
    const int batch = row0 >> 11;
    const int rl_ = threadIdx.x & 31;
    const int jslot = threadIdx.x >> 5;
    const int wave = threadIdx.x >> 6;
    const int lane = threadIdx.x & 63;
    const size_t bb = (size_t)batch << 11;
    const float4* Q = S2 + bb + jslot * JCHUNK;
    const float* C = c_g + bb + jslot * JCHUNK;
    float4 p = S1[row0 + rl_];
    float aU = 0.f;
#pragma unroll 4
    for (int j = 0; j < JCHUNK; ++j) {
        float4 q = Q[j];
        float cw = C[j];
        float dx = p.x - q.x, dy = p.y - q.y, dz = p.z - q.z;
        float d2 = fmaf(dx, dx, fmaf(dy, dy, dz * dz));
        aU = fmaf(cw, fsqrt(d2), aU);
    }
    aU += __shfl_xor(aU, 32, 64);
    if (lane < 32) redU[wave * RPB + lane] = aU;
    __syncthreads();
    if (threadIdx.x < RPB) {
        float uu = 0.f;
#pragma unroll
        for (int w = 0; w < NW; ++w) uu += redU[w * RPB + threadIdx.x];
        int gi = row0 + threadIdx.x;
        float val = costrow[gi] + f_g[gi] * uu;
#pragma unroll
        for (int off = 1; off < 32; off <<= 1) val += __shfl_xor(val, off, 64);
        if (threadIdx.x == 0) atomicAdd(&out[batch], val);
    }
}

extern "C" void kernel_launch(void* const* d_in, const int* in_sizes, int n_in,
                              void* d_out, int out_size, void* d_ws, size_t ws_size,
                              hipStream_t stream) {
    const float* xyz1 = (const float*)d_in[0];
    const float* xyz2 = (const float*)d_in[1];
    float* out = (float*)d_out;
    const int b = out_size;                 // 8
    const int n = in_sizes[0] / (3 * b);    // 2048
    const int m = in_sizes[1] / (3 * b);    // 2048
    const int bn = b * n, bm = b * m;

    float4* S1 = (float4*)d_ws;             // bn
    float4* S2 = S1 + bn;                   // bm
    float* f       = (float*)(S2 + bm);     // bn
    float* c       = f + bn;                // bm
    float* remR    = c + bm;                // bm
    float* remL    = remR + bm;             // bn
    float* costrow = remL + bn;             // bn

    const float multiL = (float)((m / n > 1) ? (m / n) : 1);
    const float multiR = (float)((n / m > 1) ? (n / m) : 1);

    dim3 blk(BT);
    dim3 gFat(bn / RPB);                    // 512 blocks = 2/CU
    const int prepN = (bn > bm ? bn : bm);
    k_prep<<<dim3((prepN + 255) / 256), dim3(256), 0, stream>>>(
        xyz1, xyz2, S1, S2, out, bn, bm, b);

    const float kk0 = -16384.f * L2E;       // level -4^7
    k_A0<<<gFat, blk, 0, stream>>>(S1, S2, f, kk0, multiL, multiR);

    for (int t = 0; t < 10; ++t) {
        const float kk = (t < 9) ? -exp2f(2.f * (float)(7 - t)) * L2E : 0.f;
        if (t == 0)
            k_B<true><<<gFat, blk, 0, stream>>>(S1, S2, f, remR, c, kk, multiR);
        else
            k_B<false><<<gFat, blk, 0, stream>>>(S1, S2, f, remR, c, kk, multiR);

        if (t < 8) {
            const float kp = kk * 0.25f;                 // = kk_{t+1}
            const float rsq = 1.f / sqrtf(-kp);
            if (t == 0)
                k_CA<1, true><<<gFat, blk, 0, stream>>>(S1, S2, f, c, remR, remL,
                                                        costrow, kp, rsq, multiL);
            else
                k_CA<1, false><<<gFat, blk, 0, stream>>>(S1, S2, f, c, remR, remL,
                                                         costrow, kp, rsq, multiL);
        } else if (t == 8) {
            const float kp = -0.25f * L2E;               // kk_8
            const float rsq = 1.f / sqrtf(0.25f * L2E);
            k_CA<2, false><<<gFat, blk, 0, stream>>>(S1, S2, f, c, remR, remL,
                                                     costrow, kp, rsq, multiL);
        } else {
            k_C9<<<gFat, blk, 0, stream>>>(S1, S2, f, c, costrow, out);
        }
    }
}